// Round 7
// baseline (226.931 us; speedup 1.0000x reference)
//
#include <hip/hip_runtime.h>

#define Bz 4
#define Nn 1024
#define Dd 1024
#define Hh 16
#define HD 64
#define SCALE 0.125f
#define LN_EPS 1e-5f

typedef __attribute__((ext_vector_type(8))) __bf16 bf16x8;
typedef __attribute__((ext_vector_type(4))) float f32x4;

static __device__ inline unsigned short f2bf(float f) {
    unsigned int u = __float_as_uint(f);
    u += 0x7fffu + ((u >> 16) & 1u);   // round-to-nearest-even
    return (unsigned short)(u >> 16);
}

static __device__ inline float bf2f(unsigned short s) {
    return __uint_as_float((unsigned)s << 16);
}

static __device__ inline bf16x8 ldfrag(const unsigned short* p) {
    return *(const bf16x8*)p;
}

static __device__ __forceinline__ void glds16(const unsigned short* g, unsigned short* l) {
    __builtin_amdgcn_global_load_lds((const __attribute__((address_space(1))) void*)g,
                                     (__attribute__((address_space(3))) void*)l, 16, 0, 0);
}

// ---------------- LayerNorm: x[4096][1024] fp32 -> xn bf16 ----------------
__global__ __launch_bounds__(256) void ln_kernel(const float* __restrict__ x,
                                                 const float* __restrict__ gamma,
                                                 const float* __restrict__ beta,
                                                 unsigned short* __restrict__ xn) {
    int row = blockIdx.x;
    int t = threadIdx.x;
    const float* xr = x + (size_t)row * Dd;
    float4 v = ((const float4*)xr)[t];
    float s = v.x + v.y + v.z + v.w;
    float ss = v.x * v.x + v.y * v.y + v.z * v.z + v.w * v.w;
    for (int o = 32; o > 0; o >>= 1) {
        s += __shfl_down(s, o);
        ss += __shfl_down(ss, o);
    }
    __shared__ float red[8];
    int wid = t >> 6;
    if ((t & 63) == 0) { red[wid * 2] = s; red[wid * 2 + 1] = ss; }
    __syncthreads();
    float tot = red[0] + red[2] + red[4] + red[6];
    float tot2 = red[1] + red[3] + red[5] + red[7];
    float mu = tot * (1.0f / Dd);
    float var = tot2 * (1.0f / Dd) - mu * mu;
    float inv = rsqrtf(var + LN_EPS);
    float4 g = ((const float4*)gamma)[t];
    float4 b = ((const float4*)beta)[t];
    ushort4 o4;
    o4.x = f2bf((v.x - mu) * inv * g.x + b.x);
    o4.y = f2bf((v.y - mu) * inv * g.y + b.y);
    o4.z = f2bf((v.z - mu) * inv * g.z + b.z);
    o4.w = f2bf((v.w - mu) * inv * g.w + b.w);
    ((ushort4*)(xn + (size_t)row * Dd))[t] = o4;
}

// ------------- transpose fp32 [rows][cols] -> bf16 [cols][rows] -----------
__global__ __launch_bounds__(256) void transpose_bf16(const float* __restrict__ in,
                                                      unsigned short* __restrict__ out,
                                                      int rows, int cols) {
    __shared__ float tile[32][33];
    int c0 = blockIdx.x * 32, r0 = blockIdx.y * 32;
    int tx = threadIdx.x, ty = threadIdx.y;
    for (int i = 0; i < 32; i += 8)
        tile[ty + i][tx] = in[(size_t)(r0 + ty + i) * cols + c0 + tx];
    __syncthreads();
    for (int i = 0; i < 32; i += 8)
        out[(size_t)(c0 + ty + i) * rows + r0 + tx] = f2bf(tile[tx][ty + i]);
}

// -------------------- fp32 -> bf16 convert (sim) --------------------------
__global__ __launch_bounds__(256) void conv_bf16(const float* __restrict__ in,
                                                 unsigned short* __restrict__ out) {
    int i = blockIdx.x * 256 + threadIdx.x;
    float4 v = ((const float4*)in)[i];
    ushort4 o;
    o.x = f2bf(v.x); o.y = f2bf(v.y); o.z = f2bf(v.z); o.w = f2bf(v.w);
    ((ushort4*)out)[i] = o;
}

// ====== GEMM body: 128x128 tile, BK=32, DOUBLE-BUFFERED, 1 barrier/iter ====
// All staging glds issued right after the barrier, consumed after the NEXT
// barrier -> prefetch latency hidden behind 16 MFMAs. LDS 32 KB total.

// -------- QKV GEMM: xn[4096][1024] @ wqkvT[3072][1024] -> q/k/vt scatter ----
__global__ __launch_bounds__(256) void gemm_qkv(const unsigned short* __restrict__ A,
                                                const unsigned short* __restrict__ Bt,
                                                unsigned short* __restrict__ qb,
                                                unsigned short* __restrict__ kb,
                                                unsigned short* __restrict__ vtb) {
    __shared__ unsigned short sA[8192], sB[8192];   // 2 bufs x [128][32]
    int tid = threadIdx.x;
    int w = tid >> 6, lane = tid & 63, lrow = lane & 15, quad = lane >> 4;
    int wm = w >> 1, wn = w & 1;
    int rowbase = blockIdx.y * 128;
    int colbase = blockIdx.x * 128;

    int srow = tid >> 2;
    int kcl = tid & 3;
    int kcg = (kcl - (srow >> 1)) & 3;
    const unsigned short* gA0 = A + (size_t)(rowbase + srow) * 1024 + kcg * 8;
    const unsigned short* gA1 = gA0 + (size_t)64 * 1024;
    const unsigned short* gB0 = Bt + (size_t)(colbase + srow) * 1024 + kcg * 8;
    const unsigned short* gB1 = gB0 + (size_t)64 * 1024;
    unsigned short* lA = sA + w * 512;
    unsigned short* lB = sB + w * 512;

    int ssw = (quad + (lrow >> 1)) & 3;
    const unsigned short* fa0 = sA + (wm * 64 + lrow) * 32 + ssw * 8;
    const unsigned short* fb0 = sB + (wn * 64 + lrow) * 32 + ssw * 8;

    f32x4 acc[4][4];
    #pragma unroll
    for (int i = 0; i < 4; i++)
        #pragma unroll
        for (int j = 0; j < 4; j++)
            acc[i][j] = (f32x4){0.f, 0.f, 0.f, 0.f};

    // prologue: stage k-slab 0 into buffer 0
    glds16(gA0, lA);
    glds16(gA1, lA + 2048);
    glds16(gB0, lB);
    glds16(gB1, lB + 2048);

    for (int it = 0; it < 32; it++) {
        int cb = it & 1;
        __syncthreads();                       // stage(it) resident; buf cb^1 free
        if (it < 31) {
            int k0 = (it + 1) * 32;
            int bo = (cb ^ 1) * 4096;
            glds16(gA0 + k0, lA + bo);
            glds16(gA1 + k0, lA + bo + 2048);
            glds16(gB0 + k0, lB + bo);
            glds16(gB1 + k0, lB + bo + 2048);
        }
        const unsigned short* fa = fa0 + cb * 4096;
        const unsigned short* fb = fb0 + cb * 4096;
        bf16x8 a[4], b[4];
        #pragma unroll
        for (int i = 0; i < 4; i++) a[i] = *(const bf16x8*)(fa + i * 512);
        #pragma unroll
        for (int j = 0; j < 4; j++) b[j] = *(const bf16x8*)(fb + j * 512);
        #pragma unroll
        for (int i = 0; i < 4; i++)
            #pragma unroll
            for (int j = 0; j < 4; j++)
                acc[i][j] = __builtin_amdgcn_mfma_f32_16x16x32_bf16(a[i], b[j], acc[i][j], 0, 0, 0);
    }

    if (colbase < 2048) {
        // q/k columns: e-contiguous scalar stores
        #pragma unroll
        for (int j = 0; j < 4; j++) {
            int col = colbase + wn * 64 + j * 16 + lrow;
            int s = col >> 10, rem = col & 1023;
            int h = rem >> 6, e = rem & 63;
            unsigned short* dst = (s == 0) ? qb : kb;
            #pragma unroll
            for (int i = 0; i < 4; i++) {
                #pragma unroll
                for (int r = 0; r < 4; r++) {
                    int R = rowbase + wm * 64 + i * 16 + quad * 4 + r;
                    int bb = R >> 10, n = R & 1023;
                    dst[(((size_t)(bb * Hh + h)) * Nn + n) * HD + e] = f2bf(acc[i][j][r]);
                }
            }
        }
    } else {
        // v columns: transpose 64x64 wave tile through LDS -> b64 n-contiguous
        int bb = rowbase >> 10;
        int nbase = (rowbase & 1023) + wm * 64;
        unsigned short* sc = sA + w * 2048;      // per-wave scratch [16][68]
        int er = lane >> 2, nc = lane & 3;
        #pragma unroll
        for (int j = 0; j < 4; j++) {
            __syncthreads();
            int ebase = colbase + wn * 64 + j * 16 - 2048;
            int h = ebase >> 6, e0 = ebase & 63;
            #pragma unroll
            for (int i = 0; i < 4; i++) {
                uint2 pk;
                pk.x = (unsigned)f2bf(acc[i][j][0]) | ((unsigned)f2bf(acc[i][j][1]) << 16);
                pk.y = (unsigned)f2bf(acc[i][j][2]) | ((unsigned)f2bf(acc[i][j][3]) << 16);
                *(uint2*)(sc + lrow * 68 + i * 16 + quad * 4) = pk;
            }
            __syncthreads();
            unsigned short* vrow = vtb + ((size_t)((bb * Hh + h) * HD) + e0 + er) * Nn + nbase;
            #pragma unroll
            for (int c = 0; c < 4; c++) {
                uint2 v = *(const uint2*)(sc + er * 68 + c * 16 + nc * 4);
                *(uint2*)(vrow + c * 16 + nc * 4) = v;
            }
        }
    }
}

// ---- proj GEMM: aout[4096][1024] @ wprojT[1024][1024] + bias + x -> out ----
__global__ __launch_bounds__(256) void gemm_proj(const unsigned short* __restrict__ A,
                                                 const unsigned short* __restrict__ Bt,
                                                 const float* __restrict__ bias,
                                                 const float* __restrict__ x,
                                                 float* __restrict__ out) {
    __shared__ unsigned short sA[8192], sB[8192];
    int tid = threadIdx.x;
    int w = tid >> 6, lane = tid & 63, lrow = lane & 15, quad = lane >> 4;
    int wm = w >> 1, wn = w & 1;
    int rowbase = blockIdx.y * 128;
    int colbase = blockIdx.x * 128;

    int srow = tid >> 2;
    int kcl = tid & 3;
    int kcg = (kcl - (srow >> 1)) & 3;
    const unsigned short* gA0 = A + (size_t)(rowbase + srow) * 1024 + kcg * 8;
    const unsigned short* gA1 = gA0 + (size_t)64 * 1024;
    const unsigned short* gB0 = Bt + (size_t)(colbase + srow) * 1024 + kcg * 8;
    const unsigned short* gB1 = gB0 + (size_t)64 * 1024;
    unsigned short* lA = sA + w * 512;
    unsigned short* lB = sB + w * 512;

    int ssw = (quad + (lrow >> 1)) & 3;
    const unsigned short* fa0 = sA + (wm * 64 + lrow) * 32 + ssw * 8;
    const unsigned short* fb0 = sB + (wn * 64 + lrow) * 32 + ssw * 8;

    f32x4 acc[4][4];
    #pragma unroll
    for (int i = 0; i < 4; i++)
        #pragma unroll
        for (int j = 0; j < 4; j++)
            acc[i][j] = (f32x4){0.f, 0.f, 0.f, 0.f};

    glds16(gA0, lA);
    glds16(gA1, lA + 2048);
    glds16(gB0, lB);
    glds16(gB1, lB + 2048);

    for (int it = 0; it < 32; it++) {
        int cb = it & 1;
        __syncthreads();
        if (it < 31) {
            int k0 = (it + 1) * 32;
            int bo = (cb ^ 1) * 4096;
            glds16(gA0 + k0, lA + bo);
            glds16(gA1 + k0, lA + bo + 2048);
            glds16(gB0 + k0, lB + bo);
            glds16(gB1 + k0, lB + bo + 2048);
        }
        const unsigned short* fa = fa0 + cb * 4096;
        const unsigned short* fb = fb0 + cb * 4096;
        bf16x8 a[4], b[4];
        #pragma unroll
        for (int i = 0; i < 4; i++) a[i] = *(const bf16x8*)(fa + i * 512);
        #pragma unroll
        for (int j = 0; j < 4; j++) b[j] = *(const bf16x8*)(fb + j * 512);
        #pragma unroll
        for (int i = 0; i < 4; i++)
            #pragma unroll
            for (int j = 0; j < 4; j++)
                acc[i][j] = __builtin_amdgcn_mfma_f32_16x16x32_bf16(a[i], b[j], acc[i][j], 0, 0, 0);
    }

    #pragma unroll
    for (int j = 0; j < 4; j++) {
        int col = colbase + wn * 64 + j * 16 + lrow;
        float bc = bias[col];
        #pragma unroll
        for (int i = 0; i < 4; i++) {
            #pragma unroll
            for (int r = 0; r < 4; r++) {
                int R = rowbase + wm * 64 + i * 16 + quad * 4 + r;
                out[(size_t)R * 1024 + col] = acc[i][j][r] + bc + x[(size_t)R * 1024 + col];
            }
        }
    }
}

// ===== fused attention v5: dbuf K/V, 1 barrier/iter, sim prefetched ========
// Swapped QK (S = K·Q^T); wave owns 32 q-rows; m-tile = 64 keys; no max pass.
// All VMEM (glds K/V + sim regs) issued right after the barrier for tile
// mt+1; compute(mt) uses only data drained by the previous barrier.
#define PSTR 72   // sP row stride in shorts (144 B)
__global__ __launch_bounds__(256) void attn_kernel(const unsigned short* __restrict__ qb,
                                                   const unsigned short* __restrict__ kb,
                                                   const unsigned short* __restrict__ vtb,
                                                   const unsigned short* __restrict__ simb,
                                                   const float* __restrict__ swl,
                                                   unsigned short* __restrict__ aout) {
    int h = blockIdx.y, bb = blockIdx.z;
    int n0 = blockIdx.x * 128;
    int tid = threadIdx.x;
    int w = tid >> 6, lane = tid & 63;
    int lrow = lane & 15, quad = lane >> 4;
    const unsigned short* q = qb + ((size_t)(bb * Hh + h)) * Nn * HD;
    const unsigned short* k = kb + ((size_t)(bb * Hh + h)) * Nn * HD;
    const unsigned short* vt = vtb + ((size_t)(bb * Hh + h)) * HD * Nn;
    float alpha = 1.f / (1.f + __expf(-swl[0]));
    float c1 = (1.f - alpha) * SCALE;

    __shared__ unsigned short sK[8192];        // 2 bufs x [64 keys][64 d]
    __shared__ unsigned short sV[8192];        // 2 bufs x [64 e][64 keys]
    __shared__ unsigned short sP[128 * PSTR];  // [128 qrows][64 keys + pad]

    int qr0 = n0 + w * 32;
    bf16x8 qf[2][2];
    #pragma unroll
    for (int g = 0; g < 2; g++) {
        qf[g][0] = ldfrag(q + (size_t)(qr0 + g * 16 + lrow) * HD + quad * 8);
        qf[g][1] = ldfrag(q + (size_t)(qr0 + g * 16 + lrow) * HD + 32 + quad * 8);
    }

    f32x4 o[2][4];
    #pragma unroll
    for (int g = 0; g < 2; g++)
        #pragma unroll
        for (int et = 0; et < 4; et++) o[g][et] = (f32x4){0.f, 0.f, 0.f, 0.f};
    float rsum[2] = {0.f, 0.f};

    int bs0 = (quad + (lrow >> 1)) & 7;
    int bs1 = (4 + quad + (lrow >> 1)) & 7;
    unsigned short* sPw = sP + (w * 32) * PSTR;

    // thread's staging slots (two 16B chunks per matrix per tile)
    int srow0 = tid >> 3, cg0 = ((tid & 7) - (srow0 >> 1)) & 7;
    int srow1 = (256 + tid) >> 3, cg1 = ((tid & 7) - (srow1 >> 1)) & 7;
    const unsigned short* simrow0 = simb + (size_t)(qr0 + lrow) * Nn + quad * 4;
    const unsigned short* simrow1 = simb + (size_t)(qr0 + 16 + lrow) * Nn + quad * 4;

    ushort4 smc[4][2], smn[4][2];

    // prologue: stage tile 0 into buf 0; load sim tile 0
    glds16(k + (size_t)srow0 * HD + cg0 * 8, sK + w * 512);
    glds16(k + (size_t)srow1 * HD + cg1 * 8, sK + 2048 + w * 512);
    glds16(vt + (size_t)srow0 * Nn + cg0 * 8, sV + w * 512);
    glds16(vt + (size_t)srow1 * Nn + cg1 * 8, sV + 2048 + w * 512);
    #pragma unroll
    for (int ks = 0; ks < 4; ks++) {
        smc[ks][0] = *(const ushort4*)(simrow0 + ks * 16);
        smc[ks][1] = *(const ushort4*)(simrow1 + ks * 16);
    }

    for (int mt = 0; mt < 16; mt++) {
        int cb = mt & 1;
        __syncthreads();    // tile mt resident (vmcnt drained); buf cb^1 free
        if (mt < 15) {
            int m0 = (mt + 1) * 64;
            int bo = (cb ^ 1) * 4096;
            glds16(k + (size_t)(m0 + srow0) * HD + cg0 * 8, sK + bo + w * 512);
            glds16(k + (size_t)(m0 + srow1) * HD + cg1 * 8, sK + bo + 2048 + w * 512);
            glds16(vt + (size_t)srow0 * Nn + m0 + cg0 * 8, sV + bo + w * 512);
            glds16(vt + (size_t)srow1 * Nn + m0 + cg1 * 8, sV + bo + 2048 + w * 512);
            #pragma unroll
            for (int ks = 0; ks < 4; ks++) {
                smn[ks][0] = *(const ushort4*)(simrow0 + m0 + ks * 16);
                smn[ks][1] = *(const ushort4*)(simrow1 + m0 + ks * 16);
            }
        }

        const unsigned short* sKc = sK + cb * 4096;
        const unsigned short* sVc = sV + cb * 4096;

        // QK^T (swapped: a=K, b=Q) + blend + exp -> P (b64 writes)
        #pragma unroll
        for (int ks = 0; ks < 4; ks++) {
            const unsigned short* kr = sKc + (ks * 16 + lrow) * 64;
            bf16x8 ak0 = *(const bf16x8*)(kr + bs0 * 8);
            bf16x8 ak1 = *(const bf16x8*)(kr + bs1 * 8);
            #pragma unroll
            for (int g = 0; g < 2; g++) {
                f32x4 c = (f32x4){0.f, 0.f, 0.f, 0.f};
                c = __builtin_amdgcn_mfma_f32_16x16x32_bf16(ak0, qf[g][0], c, 0, 0, 0);
                c = __builtin_amdgcn_mfma_f32_16x16x32_bf16(ak1, qf[g][1], c, 0, 0, 0);
                const unsigned short* smp = (const unsigned short*)&smc[ks][g];
                float e0 = __expf(c1 * c[0] + alpha * bf2f(smp[0]));
                float e1 = __expf(c1 * c[1] + alpha * bf2f(smp[1]));
                float e2 = __expf(c1 * c[2] + alpha * bf2f(smp[2]));
                float e3 = __expf(c1 * c[3] + alpha * bf2f(smp[3]));
                rsum[g] += (e0 + e1) + (e2 + e3);
                uint2 pk;
                pk.x = (__float_as_uint(e0) >> 16) | (__float_as_uint(e1) & 0xffff0000u);
                pk.y = (__float_as_uint(e2) >> 16) | (__float_as_uint(e3) & 0xffff0000u);
                *(uint2*)(sPw + (g * 16 + lrow) * PSTR + ks * 16 + quad * 4) = pk;
            }
        }

        // PV: O[32 qrows][64 e] += P[32][64] @ V[64][64]
        #pragma unroll
        for (int ms = 0; ms < 2; ms++) {
            bf16x8 pa[2];
            #pragma unroll
            for (int g = 0; g < 2; g++)
                pa[g] = *(const bf16x8*)(sPw + (g * 16 + lrow) * PSTR + ms * 32 + quad * 8);
            #pragma unroll
            for (int et = 0; et < 4; et++) {
                int e = et * 16 + lrow;
                int slot = (ms * 4 + quad + (e >> 1)) & 7;
                bf16x8 vb = *(const bf16x8*)(sVc + e * 64 + slot * 8);
                #pragma unroll
                for (int g = 0; g < 2; g++)
                    o[g][et] = __builtin_amdgcn_mfma_f32_16x16x32_bf16(pa[g], vb, o[g][et], 0, 0, 0);
            }
        }

        // rotate sim regs
        #pragma unroll
        for (int ks = 0; ks < 4; ks++) {
            smc[ks][0] = smn[ks][0];
            smc[ks][1] = smn[ks][1];
        }
    }

    #pragma unroll
    for (int g = 0; g < 2; g++) {
        rsum[g] += __shfl_xor(rsum[g], 16);
        rsum[g] += __shfl_xor(rsum[g], 32);
    }

    #pragma unroll
    for (int g = 0; g < 2; g++)
        #pragma unroll
        for (int r = 0; r < 4; r++) {
            float inv = 1.f / __shfl(rsum[g], quad * 4 + r);
            int qn = qr0 + g * 16 + quad * 4 + r;
            #pragma unroll
            for (int et = 0; et < 4; et++)
                aout[((size_t)bb * Nn + qn) * Dd + h * HD + et * 16 + lrow]
                    = f2bf(o[g][et][r] * inv);
        }
}

extern "C" void kernel_launch(void* const* d_in, const int* in_sizes, int n_in,
                              void* d_out, int out_size, void* d_ws, size_t ws_size,
                              hipStream_t stream) {
    const float* x      = (const float*)d_in[0];
    const float* gamma  = (const float*)d_in[1];
    const float* beta   = (const float*)d_in[2];
    const float* w_qkv  = (const float*)d_in[3];
    const float* w_proj = (const float*)d_in[4];
    const float* b_proj = (const float*)d_in[5];
    const float* swl    = (const float*)d_in[6];
    const float* sim    = (const float*)d_in[7];
    float* out = (float*)d_out;

    unsigned short* ws = (unsigned short*)d_ws;
    unsigned short* xn     = ws;                  // 4096*1024
    unsigned short* wqkvT  = xn + 4194304;        // 3072*1024
    unsigned short* wprojT = wqkvT + 3145728;     // 1024*1024
    unsigned short* qb     = wprojT + 1048576;    // 4*16*1024*64
    unsigned short* kb     = qb + 4194304;
    unsigned short* vtb    = kb + 4194304;
    unsigned short* aout   = vtb + 4194304;       // 4096*1024
    unsigned short* simb   = xn;                  // aliases xn (dead after gemm_qkv)

    transpose_bf16<<<dim3(3072 / 32, 1024 / 32), dim3(32, 8), 0, stream>>>(w_qkv, wqkvT, 1024, 3072);
    transpose_bf16<<<dim3(1024 / 32, 1024 / 32), dim3(32, 8), 0, stream>>>(w_proj, wprojT, 1024, 1024);
    ln_kernel<<<4096, 256, 0, stream>>>(x, gamma, beta, xn);
    gemm_qkv<<<dim3(24, 32), 256, 0, stream>>>(xn, wqkvT, qb, kb, vtb);
    conv_bf16<<<1024, 256, 0, stream>>>(sim, simb);
    attn_kernel<<<dim3(8, 16, 4), 256, 0, stream>>>(qb, kb, vtb, simb, swl, aout);
    gemm_proj<<<dim3(8, 32), 256, 0, stream>>>(aout, wprojT, b_proj, x, out);
}

// Round 8
// 199.438 us; speedup vs baseline: 1.1379x; 1.1379x over previous
//
#include <hip/hip_runtime.h>

#define Bz 4
#define Nn 1024
#define Dd 1024
#define Hh 16
#define HD 64
#define SCALE 0.125f
#define LN_EPS 1e-5f

typedef __attribute__((ext_vector_type(8))) __bf16 bf16x8;
typedef __attribute__((ext_vector_type(4))) float f32x4;

static __device__ inline unsigned short f2bf(float f) {
    unsigned int u = __float_as_uint(f);
    u += 0x7fffu + ((u >> 16) & 1u);   // round-to-nearest-even
    return (unsigned short)(u >> 16);
}

static __device__ inline bf16x8 ldfrag(const unsigned short* p) {
    return *(const bf16x8*)p;
}

static __device__ __forceinline__ void glds16(const unsigned short* g, unsigned short* l) {
    __builtin_amdgcn_global_load_lds((const __attribute__((address_space(1))) void*)g,
                                     (__attribute__((address_space(3))) void*)l, 16, 0, 0);
}

// ===== prep: LN (blocks 0..4095) + transpose w_qkv (4096..7167) +
//             transpose w_proj (7168..8191), all 256-thread blocks ==========
__global__ __launch_bounds__(256) void prep_kernel(const float* __restrict__ x,
                                                   const float* __restrict__ gamma,
                                                   const float* __restrict__ beta,
                                                   unsigned short* __restrict__ xn,
                                                   const float* __restrict__ w_qkv,
                                                   unsigned short* __restrict__ wqkvT,
                                                   const float* __restrict__ w_proj,
                                                   unsigned short* __restrict__ wprojT) {
    __shared__ float tile[32][33];
    int blk = blockIdx.x;
    int tid = threadIdx.x;

    if (blk < 4096) {
        // -------- LayerNorm row --------
        const float* xr = x + (size_t)blk * Dd;
        float4 v = ((const float4*)xr)[tid];
        float s = v.x + v.y + v.z + v.w;
        float ss = v.x * v.x + v.y * v.y + v.z * v.z + v.w * v.w;
        for (int o = 32; o > 0; o >>= 1) {
            s += __shfl_down(s, o);
            ss += __shfl_down(ss, o);
        }
        float* red = &tile[0][0];
        int wid = tid >> 6;
        if ((tid & 63) == 0) { red[wid * 2] = s; red[wid * 2 + 1] = ss; }
        __syncthreads();
        float tot = red[0] + red[2] + red[4] + red[6];
        float tot2 = red[1] + red[3] + red[5] + red[7];
        float mu = tot * (1.0f / Dd);
        float var = tot2 * (1.0f / Dd) - mu * mu;
        float inv = rsqrtf(var + LN_EPS);
        float4 g = ((const float4*)gamma)[tid];
        float4 b = ((const float4*)beta)[tid];
        ushort4 o4;
        o4.x = f2bf((v.x - mu) * inv * g.x + b.x);
        o4.y = f2bf((v.y - mu) * inv * g.y + b.y);
        o4.z = f2bf((v.z - mu) * inv * g.z + b.z);
        o4.w = f2bf((v.w - mu) * inv * g.w + b.w);
        ((ushort4*)(xn + (size_t)blk * Dd))[tid] = o4;
    } else {
        // -------- weight transpose fp32 [rows][cols] -> bf16 [cols][rows] ----
        const float* in;
        unsigned short* out;
        int cols, c0, r0;
        if (blk < 7168) {
            int idx = blk - 4096;            // 96 x-tiles, 32 y-tiles
            in = w_qkv; out = wqkvT; cols = 3072;
            c0 = (idx % 96) * 32; r0 = (idx / 96) * 32;
        } else {
            int idx = blk - 7168;            // 32 x 32 tiles
            in = w_proj; out = wprojT; cols = 1024;
            c0 = (idx % 32) * 32; r0 = (idx / 32) * 32;
        }
        int tx = tid & 31, ty = tid >> 5;    // 32 x 8
        #pragma unroll
        for (int i = 0; i < 32; i += 8)
            tile[ty + i][tx] = in[(size_t)(r0 + ty + i) * cols + c0 + tx];
        __syncthreads();
        #pragma unroll
        for (int i = 0; i < 32; i += 8)
            out[(size_t)(c0 + ty + i) * 1024 + r0 + tx] = f2bf(tile[tx][ty + i]);
    }
}

// ========== GEMM body: 128x128 tile, BK=64 (32 MFMA / barrier pair) ========
// LDS [128 rows][64 shorts]; chunk (16B) slot swizzle: slot s holds global
// chunk (s - (row>>1))&7 -> fragment b128 reads rotate start bank per row pair.

// -------- QKV GEMM: xn[4096][1024] @ wqkvT[3072][1024] -> q/k/vt scatter ----
__global__ __launch_bounds__(256) void gemm_qkv(const unsigned short* __restrict__ A,
                                                const unsigned short* __restrict__ Bt,
                                                unsigned short* __restrict__ qb,
                                                unsigned short* __restrict__ kb,
                                                unsigned short* __restrict__ vtb) {
    __shared__ unsigned short sA[8192], sB[8192];
    int tid = threadIdx.x;
    int w = tid >> 6, lane = tid & 63, lrow = lane & 15, quad = lane >> 4;
    int wm = w >> 1, wn = w & 1;
    int rowbase = blockIdx.y * 128;
    int colbase = blockIdx.x * 128;

    int srow = tid >> 3;
    int gch = ((tid & 7) - (srow >> 1)) & 7;
    const unsigned short* gA = A + (size_t)(rowbase + srow) * 1024 + gch * 8;
    const unsigned short* gB = Bt + (size_t)(colbase + srow) * 1024 + gch * 8;
    unsigned short* lA = sA + w * 512;
    unsigned short* lB = sB + w * 512;

    int bs0 = ((quad + (lrow >> 1)) & 7) * 8;
    int bs1 = ((4 + quad + (lrow >> 1)) & 7) * 8;
    const unsigned short* fa = sA + (wm * 64 + lrow) * 64;
    const unsigned short* fb = sB + (wn * 64 + lrow) * 64;

    f32x4 acc[4][4];
    #pragma unroll
    for (int i = 0; i < 4; i++)
        #pragma unroll
        for (int j = 0; j < 4; j++)
            acc[i][j] = (f32x4){0.f, 0.f, 0.f, 0.f};

    for (int k0 = 0; k0 < 1024; k0 += 64) {
        __syncthreads();
        #pragma unroll
        for (int c = 0; c < 4; c++) {
            glds16(gA + (size_t)c * 32768 + k0, lA + c * 2048);
            glds16(gB + (size_t)c * 32768 + k0, lB + c * 2048);
        }
        __syncthreads();
        #pragma unroll
        for (int s = 0; s < 2; s++) {
            int bo = s ? bs1 : bs0;
            bf16x8 a[4], b[4];
            #pragma unroll
            for (int i = 0; i < 4; i++) a[i] = *(const bf16x8*)(fa + i * 1024 + bo);
            #pragma unroll
            for (int j = 0; j < 4; j++) b[j] = *(const bf16x8*)(fb + j * 1024 + bo);
            #pragma unroll
            for (int i = 0; i < 4; i++)
                #pragma unroll
                for (int j = 0; j < 4; j++)
                    acc[i][j] = __builtin_amdgcn_mfma_f32_16x16x32_bf16(a[i], b[j], acc[i][j], 0, 0, 0);
        }
    }

    if (colbase < 2048) {
        // q/k columns: e-contiguous scalar stores
        #pragma unroll
        for (int j = 0; j < 4; j++) {
            int col = colbase + wn * 64 + j * 16 + lrow;
            int s = col >> 10, rem = col & 1023;
            int h = rem >> 6, e = rem & 63;
            unsigned short* dst = (s == 0) ? qb : kb;
            #pragma unroll
            for (int i = 0; i < 4; i++) {
                #pragma unroll
                for (int r = 0; r < 4; r++) {
                    int R = rowbase + wm * 64 + i * 16 + quad * 4 + r;
                    int bb = R >> 10, n = R & 1023;
                    dst[(((size_t)(bb * Hh + h)) * Nn + n) * HD + e] = f2bf(acc[i][j][r]);
                }
            }
        }
    } else {
        // v columns: transpose 64x64 wave tile through LDS -> b64 n-contiguous
        int bb = rowbase >> 10;
        int nbase = (rowbase & 1023) + wm * 64;
        unsigned short* sc = sA + w * 2048;      // per-wave scratch [16][68]
        int er = lane >> 2, nc = lane & 3;
        #pragma unroll
        for (int j = 0; j < 4; j++) {
            __syncthreads();
            int ebase = colbase + wn * 64 + j * 16 - 2048;
            int h = ebase >> 6, e0 = ebase & 63;
            #pragma unroll
            for (int i = 0; i < 4; i++) {
                uint2 pk;
                pk.x = (unsigned)f2bf(acc[i][j][0]) | ((unsigned)f2bf(acc[i][j][1]) << 16);
                pk.y = (unsigned)f2bf(acc[i][j][2]) | ((unsigned)f2bf(acc[i][j][3]) << 16);
                *(uint2*)(sc + lrow * 68 + i * 16 + quad * 4) = pk;
            }
            __syncthreads();
            unsigned short* vrow = vtb + ((size_t)((bb * Hh + h) * HD) + e0 + er) * Nn + nbase;
            #pragma unroll
            for (int c = 0; c < 4; c++) {
                uint2 v = *(const uint2*)(sc + er * 68 + c * 16 + nc * 4);
                *(uint2*)(vrow + c * 16 + nc * 4) = v;
            }
        }
    }
}

// ---- proj GEMM: aout[4096][1024] @ wprojT[1024][1024] + bias + x -> out ----
__global__ __launch_bounds__(256) void gemm_proj(const unsigned short* __restrict__ A,
                                                 const unsigned short* __restrict__ Bt,
                                                 const float* __restrict__ bias,
                                                 const float* __restrict__ x,
                                                 float* __restrict__ out) {
    __shared__ unsigned short sA[8192], sB[8192];
    int tid = threadIdx.x;
    int w = tid >> 6, lane = tid & 63, lrow = lane & 15, quad = lane >> 4;
    int wm = w >> 1, wn = w & 1;
    int rowbase = blockIdx.y * 128;
    int colbase = blockIdx.x * 128;

    int srow = tid >> 3;
    int gch = ((tid & 7) - (srow >> 1)) & 7;
    const unsigned short* gA = A + (size_t)(rowbase + srow) * 1024 + gch * 8;
    const unsigned short* gB = Bt + (size_t)(colbase + srow) * 1024 + gch * 8;
    unsigned short* lA = sA + w * 512;
    unsigned short* lB = sB + w * 512;

    int bs0 = ((quad + (lrow >> 1)) & 7) * 8;
    int bs1 = ((4 + quad + (lrow >> 1)) & 7) * 8;
    const unsigned short* fa = sA + (wm * 64 + lrow) * 64;
    const unsigned short* fb = sB + (wn * 64 + lrow) * 64;

    f32x4 acc[4][4];
    #pragma unroll
    for (int i = 0; i < 4; i++)
        #pragma unroll
        for (int j = 0; j < 4; j++)
            acc[i][j] = (f32x4){0.f, 0.f, 0.f, 0.f};

    for (int k0 = 0; k0 < 1024; k0 += 64) {
        __syncthreads();
        #pragma unroll
        for (int c = 0; c < 4; c++) {
            glds16(gA + (size_t)c * 32768 + k0, lA + c * 2048);
            glds16(gB + (size_t)c * 32768 + k0, lB + c * 2048);
        }
        __syncthreads();
        #pragma unroll
        for (int s = 0; s < 2; s++) {
            int bo = s ? bs1 : bs0;
            bf16x8 a[4], b[4];
            #pragma unroll
            for (int i = 0; i < 4; i++) a[i] = *(const bf16x8*)(fa + i * 1024 + bo);
            #pragma unroll
            for (int j = 0; j < 4; j++) b[j] = *(const bf16x8*)(fb + j * 1024 + bo);
            #pragma unroll
            for (int i = 0; i < 4; i++)
                #pragma unroll
                for (int j = 0; j < 4; j++)
                    acc[i][j] = __builtin_amdgcn_mfma_f32_16x16x32_bf16(a[i], b[j], acc[i][j], 0, 0, 0);
        }
    }

    #pragma unroll
    for (int j = 0; j < 4; j++) {
        int col = colbase + wn * 64 + j * 16 + lrow;
        float bc = bias[col];
        #pragma unroll
        for (int i = 0; i < 4; i++) {
            #pragma unroll
            for (int r = 0; r < 4; r++) {
                int R = rowbase + wm * 64 + i * 16 + quad * 4 + r;
                out[(size_t)R * 1024 + col] = acc[i][j][r] + bc + x[(size_t)R * 1024 + col];
            }
        }
    }
}

// ============ fused attention v4 (r6): block = (b, h, 128 q-rows) ==========
// Swapped QK (S = K·Q^T): lane holds one q-row (col=lrow), 4 consecutive keys
// (row=quad*4+r) -> P written as ds_write_b64 directly in A-frag orientation.
// Wave owns 32 q-rows. m-tile = 64 keys. No max pass. sim read as fp32.
#define PSTR 72   // sP row stride in shorts (144 B)
__global__ __launch_bounds__(256) void attn_kernel(const unsigned short* __restrict__ qb,
                                                   const unsigned short* __restrict__ kb,
                                                   const unsigned short* __restrict__ vtb,
                                                   const float* __restrict__ sim,
                                                   const float* __restrict__ swl,
                                                   unsigned short* __restrict__ aout) {
    int h = blockIdx.y, bb = blockIdx.z;
    int n0 = blockIdx.x * 128;
    int tid = threadIdx.x;
    int w = tid >> 6, lane = tid & 63;
    int lrow = lane & 15, quad = lane >> 4;
    const unsigned short* q = qb + ((size_t)(bb * Hh + h)) * Nn * HD;
    const unsigned short* k = kb + ((size_t)(bb * Hh + h)) * Nn * HD;
    const unsigned short* vt = vtb + ((size_t)(bb * Hh + h)) * HD * Nn;
    float alpha = 1.f / (1.f + __expf(-swl[0]));
    float c1 = (1.f - alpha) * SCALE;

    __shared__ unsigned short sK[4096];        // [64 keys][64 d], chunk-swizzled
    __shared__ unsigned short sV[4096];        // [64 e][64 keys], chunk-swizzled
    __shared__ unsigned short sP[128 * PSTR];  // [128 qrows][64 keys + pad]

    int qr0 = n0 + w * 32;
    bf16x8 qf[2][2];
    #pragma unroll
    for (int g = 0; g < 2; g++) {
        qf[g][0] = ldfrag(q + (size_t)(qr0 + g * 16 + lrow) * HD + quad * 8);
        qf[g][1] = ldfrag(q + (size_t)(qr0 + g * 16 + lrow) * HD + 32 + quad * 8);
    }

    f32x4 o[2][4];
    #pragma unroll
    for (int g = 0; g < 2; g++)
        #pragma unroll
        for (int et = 0; et < 4; et++) o[g][et] = (f32x4){0.f, 0.f, 0.f, 0.f};
    float rsum[2] = {0.f, 0.f};

    int bs0 = (quad + (lrow >> 1)) & 7;
    int bs1 = (4 + quad + (lrow >> 1)) & 7;
    unsigned short* sPw = sP + (w * 32) * PSTR;

    for (int m0 = 0; m0 < 1024; m0 += 64) {
        __syncthreads();
        #pragma unroll
        for (int i = 0; i < 2; i++) {
            int slot = i * 256 + tid;
            int row = slot >> 3;
            int cg = ((slot & 7) - (row >> 1)) & 7;
            glds16(k + (size_t)(m0 + row) * HD + cg * 8, sK + i * 2048 + w * 512);
        }
        #pragma unroll
        for (int i = 0; i < 2; i++) {
            int slot = i * 256 + tid;
            int row = slot >> 3;
            int cg = ((slot & 7) - (row >> 1)) & 7;
            glds16(vt + (size_t)row * Nn + m0 + cg * 8, sV + i * 2048 + w * 512);
        }
        float4 sm[4][2];
        #pragma unroll
        for (int ks = 0; ks < 4; ks++)
            #pragma unroll
            for (int g = 0; g < 2; g++)
                sm[ks][g] = *(const float4*)(sim + (size_t)(qr0 + g * 16 + lrow) * Nn
                                             + m0 + ks * 16 + quad * 4);
        __syncthreads();

        #pragma unroll
        for (int ks = 0; ks < 4; ks++) {
            const unsigned short* kr = sK + (ks * 16 + lrow) * 64;
            bf16x8 ak0 = *(const bf16x8*)(kr + bs0 * 8);
            bf16x8 ak1 = *(const bf16x8*)(kr + bs1 * 8);
            #pragma unroll
            for (int g = 0; g < 2; g++) {
                f32x4 c = (f32x4){0.f, 0.f, 0.f, 0.f};
                c = __builtin_amdgcn_mfma_f32_16x16x32_bf16(ak0, qf[g][0], c, 0, 0, 0);
                c = __builtin_amdgcn_mfma_f32_16x16x32_bf16(ak1, qf[g][1], c, 0, 0, 0);
                float e0 = __expf(c1 * c[0] + alpha * sm[ks][g].x);
                float e1 = __expf(c1 * c[1] + alpha * sm[ks][g].y);
                float e2 = __expf(c1 * c[2] + alpha * sm[ks][g].z);
                float e3 = __expf(c1 * c[3] + alpha * sm[ks][g].w);
                rsum[g] += (e0 + e1) + (e2 + e3);
                uint2 pk;
                pk.x = (__float_as_uint(e0) >> 16) | (__float_as_uint(e1) & 0xffff0000u);
                pk.y = (__float_as_uint(e2) >> 16) | (__float_as_uint(e3) & 0xffff0000u);
                *(uint2*)(sPw + (g * 16 + lrow) * PSTR + ks * 16 + quad * 4) = pk;
            }
        }

        #pragma unroll
        for (int ms = 0; ms < 2; ms++) {
            bf16x8 pa[2];
            #pragma unroll
            for (int g = 0; g < 2; g++)
                pa[g] = *(const bf16x8*)(sPw + (g * 16 + lrow) * PSTR + ms * 32 + quad * 8);
            #pragma unroll
            for (int et = 0; et < 4; et++) {
                int e = et * 16 + lrow;
                int slot = (ms * 4 + quad + (e >> 1)) & 7;
                bf16x8 vb = *(const bf16x8*)(sV + e * 64 + slot * 8);
                #pragma unroll
                for (int g = 0; g < 2; g++)
                    o[g][et] = __builtin_amdgcn_mfma_f32_16x16x32_bf16(pa[g], vb, o[g][et], 0, 0, 0);
            }
        }
    }

    #pragma unroll
    for (int g = 0; g < 2; g++) {
        rsum[g] += __shfl_xor(rsum[g], 16);
        rsum[g] += __shfl_xor(rsum[g], 32);
    }

    #pragma unroll
    for (int g = 0; g < 2; g++)
        #pragma unroll
        for (int r = 0; r < 4; r++) {
            float inv = 1.f / __shfl(rsum[g], quad * 4 + r);
            int qn = qr0 + g * 16 + quad * 4 + r;
            #pragma unroll
            for (int et = 0; et < 4; et++)
                aout[((size_t)bb * Nn + qn) * Dd + h * HD + et * 16 + lrow]
                    = f2bf(o[g][et][r] * inv);
        }
}

extern "C" void kernel_launch(void* const* d_in, const int* in_sizes, int n_in,
                              void* d_out, int out_size, void* d_ws, size_t ws_size,
                              hipStream_t stream) {
    const float* x      = (const float*)d_in[0];
    const float* gamma  = (const float*)d_in[1];
    const float* beta   = (const float*)d_in[2];
    const float* w_qkv  = (const float*)d_in[3];
    const float* w_proj = (const float*)d_in[4];
    const float* b_proj = (const float*)d_in[5];
    const float* swl    = (const float*)d_in[6];
    const float* sim    = (const float*)d_in[7];
    float* out = (float*)d_out;

    unsigned short* ws = (unsigned short*)d_ws;
    unsigned short* xn     = ws;                  // 4096*1024
    unsigned short* wqkvT  = xn + 4194304;        // 3072*1024
    unsigned short* wprojT = wqkvT + 3145728;     // 1024*1024
    unsigned short* qb     = wprojT + 1048576;    // 4*16*1024*64
    unsigned short* kb     = qb + 4194304;
    unsigned short* vtb    = kb + 4194304;
    unsigned short* aout   = vtb + 4194304;       // 4096*1024
    // total 24M shorts = 48 MB

    prep_kernel<<<8192, 256, 0, stream>>>(x, gamma, beta, xn, w_qkv, wqkvT, w_proj, wprojT);
    gemm_qkv<<<dim3(24, 32), 256, 0, stream>>>(xn, wqkvT, qb, kb, vtb);
    attn_kernel<<<dim3(8, 16, 4), 256, 0, stream>>>(qb, kb, vtb, sim, swl, aout);
    gemm_proj<<<dim3(8, 32), 256, 0, stream>>>(aout, wprojT, b_proj, x, out);
}